// Round 2
// baseline (228.522 us; speedup 1.0000x reference)
//
#include <hip/hip_runtime.h>
#include <stdint.h>

#define EPS 1e-5f

// ---------------- problem constants ----------------
#define NPTS 80000
#define CDIM 128
#define ODIM 64
#define KNBR 8
#define MSUP 1000

// ---------------- workspace layout (bytes) ----------------
#define KP2_OFF  0                 // [1000][128] f32 = 512 KB  (BN1-folded k+pe table)
#define UT_OFF   (512*1024)        // [1000][64]  f32 = 256 KB  (u = (v+pe)[j] + (v+pe)[j+64])
#define WQF_OFF  (768*1024)        // 32 frags * 64 lanes * 16B = 32 KB (Wq*s1c, A-layout, transposed GEMM)
#define W1F_OFF  (800*1024)        // 16 frags * 1KB = 16 KB (W1*s2c, A-layout, transposed GEMM)
#define W2F_OFF  (816*1024)        // 8 frags * 1KB = 8 KB (W2, B-layout)
#define C1_OFF   (824*1024)        // [64] f32 ((b1-m2)*s2c + beta2)

typedef float f32x4 __attribute__((ext_vector_type(4)));
typedef short bf16x8 __attribute__((ext_vector_type(8)));

union FragU { bf16x8 v; unsigned u[4]; };

__device__ inline unsigned pack_rne(float lo, float hi) {
  unsigned a = __builtin_bit_cast(unsigned, lo);
  unsigned b = __builtin_bit_cast(unsigned, hi);
  a += 0x7FFFu + ((a >> 16) & 1u);
  b += 0x7FFFu + ((b >> 16) & 1u);
  return (a >> 16) | (b & 0xFFFF0000u);
}

// ============================================================
// Kernel 1: per-superpoint tables kp2[m][c], uT[m][j]
//   kp2 = (sp_fea@Wk + bk + pe - m1 - bq) * s1c + beta1
//   uT  = (v+pe)[j] + (v+pe)[j+64],  v = sp_fea@Wv + bv
//   pe  = relu(bn(sp_xyz@Wp1+bp1)) @ Wp2 + bp2
// 250 blocks x 256 threads; each block: 2 m's in parallel x 2 iters
// ============================================================
__global__ __launch_bounds__(256)
void k_tables(const float* __restrict__ sp_fea, const float* __restrict__ sp_xyz,
              const float* __restrict__ Wk, const float* __restrict__ bk,
              const float* __restrict__ Wv, const float* __restrict__ bv,
              const float* __restrict__ Wp1, const float* __restrict__ bp1,
              const float* __restrict__ gp, const float* __restrict__ betap,
              const float* __restrict__ mp, const float* __restrict__ vp,
              const float* __restrict__ Wp2, const float* __restrict__ bp2,
              const float* __restrict__ g1, const float* __restrict__ beta1,
              const float* __restrict__ m1, const float* __restrict__ v1,
              const float* __restrict__ bq, char* __restrict__ ws)
{
  float* kp2 = (float*)(ws + KP2_OFF);
  float* uT  = (float*)(ws + UT_OFF);
  const int t = threadIdx.x;
  const int c = t & 127;
  const int half = t >> 7;
  __shared__ float fea[2][128];
  __shared__ float vpsh[2][128];
  for (int i = 0; i < 2; ++i) {
    const int m = blockIdx.x * 4 + half * 2 + i;
    fea[half][c] = sp_fea[m * 128 + c];
    const float x0 = sp_xyz[m*3+0], x1 = sp_xyz[m*3+1], x2 = sp_xyz[m*3+2];
    float pe = bp2[c];
    #pragma unroll
    for (int ii = 0; ii < 3; ++ii) {
      float s = bp1[ii] + x0*Wp1[0*3+ii] + x1*Wp1[1*3+ii] + x2*Wp1[2*3+ii];
      s = (s - mp[ii]) * (gp[ii] * rsqrtf(vp[ii] + EPS)) + betap[ii];
      s = fmaxf(s, 0.0f);
      pe += s * Wp2[ii*128 + c];
    }
    __syncthreads();
    float kv = bk[c], vv = bv[c];
    #pragma unroll 4
    for (int d = 0; d < 128; ++d) {
      const float f = fea[half][d];
      kv = fmaf(f, Wk[d*128 + c], kv);
      vv = fmaf(f, Wv[d*128 + c], vv);
    }
    const float s1c = g1[c] * rsqrtf(v1[c] + EPS);
    kp2[m*128 + c] = (kv + pe - m1[c] - bq[c]) * s1c + beta1[c];
    vpsh[half][c] = vv + pe;
    __syncthreads();
    if (c < 64) uT[m*64 + c] = vpsh[half][c] + vpsh[half][c + 64];
    __syncthreads();
  }
}

// ============================================================
// Kernel 2: pre-swizzle weights into MFMA fragment layout (bf16)
//  A-layout frag (16x16x32): lane holds A[m=lane&15][k=(lane>>4)*8 + jj]
//  B-layout frag           : lane holds B[k=(lane>>4)*8 + jj][n=lane&15]
// ============================================================
__global__ __launch_bounds__(256)
void k_swz(const float* __restrict__ Wq, const float* __restrict__ W1, const float* __restrict__ W2,
           const float* __restrict__ g1, const float* __restrict__ v1,
           const float* __restrict__ g2, const float* __restrict__ v2,
           const float* __restrict__ b1, const float* __restrict__ m2,
           const float* __restrict__ beta2, char* __restrict__ ws)
{
  const int tid = blockIdx.x * 256 + threadIdx.x;
  if (tid < 2048) {
    // Wqf^T A-frags: frag f = kt*8+mt ; A[m=c][k=d], Wqf[d][c]=Wq[d][c]*s1c[c]
    const int e = tid, f = e >> 6, l = e & 63;
    const int kt = f >> 3, mt = f & 7;
    const int c = mt*16 + (l & 15);
    const int d0 = kt*32 + (l >> 4)*8;
    const float sc = g1[c] * rsqrtf(v1[c] + EPS);
    uint4 u;
    u.x = pack_rne(Wq[(d0+0)*128 + c]*sc, Wq[(d0+1)*128 + c]*sc);
    u.y = pack_rne(Wq[(d0+2)*128 + c]*sc, Wq[(d0+3)*128 + c]*sc);
    u.z = pack_rne(Wq[(d0+4)*128 + c]*sc, Wq[(d0+5)*128 + c]*sc);
    u.w = pack_rne(Wq[(d0+6)*128 + c]*sc, Wq[(d0+7)*128 + c]*sc);
    *(uint4*)(ws + WQF_OFF + e*16) = u;
  } else if (tid < 3072) {
    // W1f^T A-frags: frag f = kt*4+jt ; A[m=j][k=c], W1f[c][j]=W1[c][j]*s2c[j]
    const int e = tid - 2048, f = e >> 6, l = e & 63;
    const int kt = f >> 2, jt = f & 3;
    const int j = jt*16 + (l & 15);
    const int c0 = kt*32 + (l >> 4)*8;
    const float sc = g2[j] * rsqrtf(v2[j] + EPS);
    uint4 u;
    u.x = pack_rne(W1[(c0+0)*64 + j]*sc, W1[(c0+1)*64 + j]*sc);
    u.y = pack_rne(W1[(c0+2)*64 + j]*sc, W1[(c0+3)*64 + j]*sc);
    u.z = pack_rne(W1[(c0+4)*64 + j]*sc, W1[(c0+5)*64 + j]*sc);
    u.w = pack_rne(W1[(c0+6)*64 + j]*sc, W1[(c0+7)*64 + j]*sc);
    *(uint4*)(ws + W1F_OFF + e*16) = u;
  } else if (tid < 3584) {
    // W2 B-frags: frag f = kt2*4+nt ; B[k=j][n=j']
    const int e = tid - 3072, f = e >> 6, l = e & 63;
    const int kt2 = f >> 2, nt = f & 3;
    const int jp = nt*16 + (l & 15);
    const int j0 = kt2*32 + (l >> 4)*8;
    uint4 u;
    u.x = pack_rne(W2[(j0+0)*64 + jp], W2[(j0+1)*64 + jp]);
    u.y = pack_rne(W2[(j0+2)*64 + jp], W2[(j0+3)*64 + jp]);
    u.z = pack_rne(W2[(j0+4)*64 + jp], W2[(j0+5)*64 + jp]);
    u.w = pack_rne(W2[(j0+6)*64 + jp], W2[(j0+7)*64 + jp]);
    *(uint4*)(ws + W2F_OFF + e*16) = u;
  } else if (tid < 3648) {
    const int j = tid - 3584;
    const float sc = g2[j] * rsqrtf(v2[j] + EPS);
    ((float*)(ws + C1_OFF))[j] = (b1[j] - m2[j]) * sc + beta2[j];
  }
}

// ============================================================
// Kernel 3: fused main. One wave = 16 points (= 128 (n,k) rows).
//  All LDS is WAVE-PRIVATE -> no __syncthreads anywhere (same-wave DS ops
//  are HW-ordered; compiler inserts lgkmcnt waits for the dependencies).
//  phase 1: qs[16][128] = o_p_fea_tile @ Wqf via MFMA -> wave LDS (f32)
//  phase 2: 8 groups of 16 rows:
//    X = relu(kp2[m] - qs[n])  (bf16 frags, built in regs)
//    h2 = relu(W1f^T @ X^T + c1)          -> LDS (bf16, b64 writes)
//    s2 = h2 @ W2 + b2                    (D: rows in quad*4+reg)
//    softmax over k (in-reg + shfl_xor16), bi = sum_j w*uT[m], softmax, store
// ============================================================
#define LDS_QS_PITCH 528           // bytes/row = 132 floats (2-way max bank aliasing)
#define LDS_QS_SIZE  (16*528)      // 8448 B / wave
#define LDS_H2_PITCH 144           // bytes/row = 72 halfs (16B-aligned rows)
#define LDS_H2_SIZE  (16*144)      // 2304 B / wave

__global__ __launch_bounds__(256, 2)
void k_main(const float* __restrict__ o_p_fea, const int* __restrict__ idx,
            const float* __restrict__ b2, const char* __restrict__ ws,
            float* __restrict__ out)
{
  const float*  kp2 = (const float*)(ws + KP2_OFF);
  const float*  uT  = (const float*)(ws + UT_OFF);
  const bf16x8* wqf = (const bf16x8*)(ws + WQF_OFF);
  const bf16x8* w1f = (const bf16x8*)(ws + W1F_OFF);
  const bf16x8* w2f = (const bf16x8*)(ws + W2F_OFF);
  const float*  c1  = (const float*)(ws + C1_OFF);

  __shared__ __align__(16) char lds[4*LDS_QS_SIZE + 4*LDS_H2_SIZE];
  const int wave = threadIdx.x >> 6;
  const int l = threadIdx.x & 63;
  const int quad = l >> 4, row = l & 15;
  char* qs_w = lds + wave * LDS_QS_SIZE;
  char* h2_w = lds + 4*LDS_QS_SIZE + wave * LDS_H2_SIZE;

  const int sg = blockIdx.x * 4 + wave;   // 0..4999
  const int n0 = sg * 16;

  // hoisted invariants
  bf16x8 w1r[16];
  #pragma unroll
  for (int f = 0; f < 16; ++f) w1r[f] = w1f[f*64 + l];
  bf16x8 w2r[8];
  #pragma unroll
  for (int f = 0; f < 8; ++f) w2r[f] = w2f[f*64 + l];
  f32x4 c1r[4];
  #pragma unroll
  for (int jt = 0; jt < 4; ++jt) c1r[jt] = *(const f32x4*)(c1 + jt*16 + quad*4);
  float b2r[4];
  #pragma unroll
  for (int nt = 0; nt < 4; ++nt) b2r[nt] = b2[row + nt*16];

  // ---- phase 1: qs^T = Wqf^T @ fea^T for 16 points ----
  f32x4 qa[8];
  #pragma unroll
  for (int mt = 0; mt < 8; ++mt) qa[mt] = (f32x4){0.f, 0.f, 0.f, 0.f};
  const float* feab = o_p_fea + (size_t)(n0 + row) * 128;
  #pragma unroll
  for (int kt = 0; kt < 4; ++kt) {
    f32x4 fa = *(const f32x4*)(feab + kt*32 + quad*8);
    f32x4 fb = *(const f32x4*)(feab + kt*32 + quad*8 + 4);
    FragU bu;
    bu.u[0] = pack_rne(fa[0], fa[1]);
    bu.u[1] = pack_rne(fa[2], fa[3]);
    bu.u[2] = pack_rne(fb[0], fb[1]);
    bu.u[3] = pack_rne(fb[2], fb[3]);
    #pragma unroll
    for (int mt = 0; mt < 8; ++mt)
      qa[mt] = __builtin_amdgcn_mfma_f32_16x16x32_bf16(wqf[(kt*8+mt)*64 + l], bu.v, qa[mt], 0, 0, 0);
  }
  // D: m = quad*4+reg+16*mt -> channel c ; n = row -> point. 4 consecutive c -> b128 store.
  #pragma unroll
  for (int mt = 0; mt < 8; ++mt)
    *(f32x4*)(qs_w + row*LDS_QS_PITCH + (mt*16 + quad*4)*4) = qa[mt];

  const int idx_base = n0 * 8;
  #pragma unroll 1
  for (int g = 0; g < 8; ++g) {
    const int m_r = idx[idx_base + g*16 + row];     // row r = lane&15 of this group
    const int nloc = row >> 3;                       // 0/1: which of the 2 points
    const float* qrow = (const float*)(qs_w + (g*2 + nloc) * LDS_QS_PITCH);

    // GEMM1 (transposed): h2^T = W1f^T @ X^T ; X = relu(kp2[m] - qs[n])
    f32x4 a1[4];
    #pragma unroll
    for (int jt = 0; jt < 4; ++jt) a1[jt] = (f32x4){0.f, 0.f, 0.f, 0.f};
    #pragma unroll
    for (int kt = 0; kt < 4; ++kt) {
      const int c8 = kt*32 + quad*8;
      const float* kr = kp2 + (size_t)m_r * 128 + c8;
      f32x4 ka = *(const f32x4*)kr;
      f32x4 kb = *(const f32x4*)(kr + 4);
      f32x4 q0 = *(const f32x4*)(qrow + c8);
      f32x4 q1 = *(const f32x4*)(qrow + c8 + 4);
      const float x0 = fmaxf(ka[0]-q0[0], 0.f), x1 = fmaxf(ka[1]-q0[1], 0.f);
      const float x2 = fmaxf(ka[2]-q0[2], 0.f), x3 = fmaxf(ka[3]-q0[3], 0.f);
      const float x4 = fmaxf(kb[0]-q1[0], 0.f), x5 = fmaxf(kb[1]-q1[1], 0.f);
      const float x6 = fmaxf(kb[2]-q1[2], 0.f), x7 = fmaxf(kb[3]-q1[3], 0.f);
      FragU xf;
      xf.u[0] = pack_rne(x0, x1); xf.u[1] = pack_rne(x2, x3);
      xf.u[2] = pack_rne(x4, x5); xf.u[3] = pack_rne(x6, x7);
      #pragma unroll
      for (int jt = 0; jt < 4; ++jt)
        a1[jt] = __builtin_amdgcn_mfma_f32_16x16x32_bf16(w1r[kt*4+jt], xf.v, a1[jt], 0, 0, 0);
    }
    // bn2-fold + relu + bf16 pack; D^T: n=row -> r, m=quad*4+reg+16*jt -> j (4 consecutive j)
    #pragma unroll
    for (int jt = 0; jt < 4; ++jt) {
      f32x4 v = a1[jt] + c1r[jt];
      uint2 pp;
      pp.x = pack_rne(fmaxf(v[0], 0.f), fmaxf(v[1], 0.f));
      pp.y = pack_rne(fmaxf(v[2], 0.f), fmaxf(v[3], 0.f));
      *(uint2*)(h2_w + row*LDS_H2_PITCH + (jt*16 + quad*4)*2) = pp;
    }

    // GEMM2: s2 = h2 @ W2 ; A-frag = h2[r=row][j=kt2*32+quad*8 ..+7] (b128 read)
    f32x4 a2[4];
    #pragma unroll
    for (int nt = 0; nt < 4; ++nt) a2[nt] = (f32x4){0.f, 0.f, 0.f, 0.f};
    #pragma unroll
    for (int kt2 = 0; kt2 < 2; ++kt2) {
      bf16x8 af = *(const bf16x8*)(h2_w + row*LDS_H2_PITCH + (kt2*32 + quad*8)*2);
      #pragma unroll
      for (int nt = 0; nt < 4; ++nt)
        a2[nt] = __builtin_amdgcn_mfma_f32_16x16x32_bf16(af, w2r[kt2*4+nt], a2[nt], 0, 0, 0);
    }
    // lane holds s2[r'=quad*4+reg][j'=row+16*nt]. softmax over the 8 rows of each point:
    // in-reg sum of 4 (this quad) + shfl_xor(16) (partner quad, same point).
    float e[4][4], rs[4];
    #pragma unroll
    for (int nt = 0; nt < 4; ++nt) {
      #pragma unroll
      for (int rg = 0; rg < 4; ++rg) e[nt][rg] = __expf(a2[nt][rg] + b2r[nt]);
      float s = e[nt][0] + e[nt][1] + e[nt][2] + e[nt][3];
      s += __shfl_xor(s, 16);
      rs[nt] = __builtin_amdgcn_rcpf(s);
    }
    // superpoint index for rows r' = quad*4+rg (lanes 0..15 hold rows 0..15)
    int msrc[4];
    #pragma unroll
    for (int rg = 0; rg < 4; ++rg) msrc[rg] = __shfl(m_r, quad*4 + rg);
    // bi[r'] = sum_j' w[r'][j'] * uT[m(r')][j'] ; reduce over j' (lane&15 dim)
    float bi[4] = {0.f, 0.f, 0.f, 0.f};
    #pragma unroll
    for (int rg = 0; rg < 4; ++rg) {
      const float* urow = uT + (size_t)msrc[rg] * 64 + row;
      #pragma unroll
      for (int nt = 0; nt < 4; ++nt)
        bi[rg] = fmaf(e[nt][rg] * rs[nt], urow[nt*16], bi[rg]);
    }
    #pragma unroll
    for (int rg = 0; rg < 4; ++rg) {
      float b = bi[rg];
      b += __shfl_xor(b, 1);
      b += __shfl_xor(b, 2);
      b += __shfl_xor(b, 4);
      b += __shfl_xor(b, 8);
      bi[rg] = b;
    }
    // final softmax over k (8 rows of each point): in-reg 4 + partner quad
    const float eb0 = __expf(bi[0]), eb1 = __expf(bi[1]);
    const float eb2 = __expf(bi[2]), eb3 = __expf(bi[3]);
    float sb = eb0 + eb1 + eb2 + eb3;
    sb += __shfl_xor(sb, 16);
    const float rsb = __builtin_amdgcn_rcpf(sb);
    if (row < 4) {
      const float vsel = row == 0 ? eb0 : row == 1 ? eb1 : row == 2 ? eb2 : eb3;
      out[n0*8 + g*16 + quad*4 + row] = vsel * rsb;
    }
  }
}

// ============================================================
extern "C" void kernel_launch(void* const* d_in, const int* in_sizes, int n_in,
                              void* d_out, int out_size, void* d_ws, size_t ws_size,
                              hipStream_t stream)
{
  const float* sp_fea  = (const float*)d_in[0];
  const float* sp_xyz  = (const float*)d_in[1];
  const float* o_p_fea = (const float*)d_in[2];
  // d_in[3] p_xyz unused by reference
  const float* Wq    = (const float*)d_in[4];
  const float* bq    = (const float*)d_in[5];
  const float* Wk    = (const float*)d_in[6];
  const float* bk    = (const float*)d_in[7];
  const float* Wv    = (const float*)d_in[8];
  const float* bv    = (const float*)d_in[9];
  const float* Wp1   = (const float*)d_in[10];
  const float* bp1   = (const float*)d_in[11];
  const float* gp    = (const float*)d_in[12];
  const float* betap = (const float*)d_in[13];
  const float* mp    = (const float*)d_in[14];
  const float* vp    = (const float*)d_in[15];
  const float* Wp2   = (const float*)d_in[16];
  const float* bp2   = (const float*)d_in[17];
  const float* g1    = (const float*)d_in[18];
  const float* beta1 = (const float*)d_in[19];
  const float* m1    = (const float*)d_in[20];
  const float* v1    = (const float*)d_in[21];
  const float* W1    = (const float*)d_in[22];
  const float* b1    = (const float*)d_in[23];
  const float* g2    = (const float*)d_in[24];
  const float* beta2 = (const float*)d_in[25];
  const float* m2    = (const float*)d_in[26];
  const float* v2    = (const float*)d_in[27];
  const float* W2    = (const float*)d_in[28];
  const float* b2    = (const float*)d_in[29];
  const int* c2p_idx_abs = (const int*)d_in[30];
  // d_in[31..34] c2p_idx / cluster_idx / offset / sp_offset unused by reference

  char* ws = (char*)d_ws;
  float* out = (float*)d_out;

  hipLaunchKernelGGL(k_tables, dim3(250), dim3(256), 0, stream,
                     sp_fea, sp_xyz, Wk, bk, Wv, bv, Wp1, bp1, gp, betap, mp, vp,
                     Wp2, bp2, g1, beta1, m1, v1, bq, ws);
  hipLaunchKernelGGL(k_swz, dim3(15), dim3(256), 0, stream,
                     Wq, W1, W2, g1, v1, g2, v2, b1, m2, beta2, ws);
  hipLaunchKernelGGL(k_main, dim3(1250), dim3(256), 0, stream,
                     o_p_fea, c2p_idx_abs, b2, ws, out);
}